// Round 5
// baseline (176.721 us; speedup 1.0000x reference)
//
#include <hip/hip_runtime.h>
#include <cstdint>

// Problem constants
#define B_   64
#define CI_  384
#define CO_  384
#define HW_  784
#define E_   8

typedef unsigned short ushort_t;
typedef unsigned int   uint_t;

typedef __attribute__((ext_vector_type(8))) short  bf16x8;   // 8 bf16 (4 VGPRs)
typedef __attribute__((ext_vector_type(4))) float  f32x4;    // MFMA accumulator
typedef __attribute__((ext_vector_type(4))) uint_t uint32x4; // 16B chunk

__device__ __forceinline__ ushort_t f2bf_rne(float f) {
  uint_t u = __builtin_bit_cast(uint_t, f);
  u += 0x7fffu + ((u >> 16) & 1u);
  return (ushort_t)(u >> 16);
}

// Pack truncated-bf16 of (f0 -> low ushort, f1 -> high ushort) in one v_perm_b32.
// (Proven rounds 1-2, absmax 0.0625.)
__device__ __forceinline__ uint_t pack_bf16_trunc(float f0, float f1) {
  return __builtin_amdgcn_perm(__builtin_bit_cast(uint_t, f1),   // S0 -> bytes 4..7
                               __builtin_bit_cast(uint_t, f0),   // S1 -> bytes 0..3
                               0x07060302u);                     // {f1.b3,f1.b2,f0.b3,f0.b2}
}

// ---------------------------------------------------------------------------
// Kernel 1: agg[b,o,i] = sum_e r[b,e] * w[e,o,i], stored bf16 into workspace.
// (Unchanged from round 2 — proven.)
// ---------------------------------------------------------------------------
__global__ __launch_bounds__(256) void agg_kernel(const float* __restrict__ rw,
                                                  const float* __restrict__ w,
                                                  ushort_t* __restrict__ agg) {
  __shared__ float r[B_ * E_];  // 512 routing weights
  const int tid = threadIdx.x;
  r[tid]       = rw[tid];
  r[tid + 256] = rw[tid + 256];
  const int base = blockIdx.x * 512 + tid * 2;  // flat (o,i) pair index
  float2 wv[E_];
#pragma unroll
  for (int e = 0; e < E_; ++e)
    wv[e] = *(const float2*)&w[e * (CO_ * CI_) + base];
  __syncthreads();
  const int b0 = blockIdx.y * 16;
#pragma unroll 4
  for (int bi = 0; bi < 16; ++bi) {
    const int b = b0 + bi;
    float ax = 0.f, ay = 0.f;
#pragma unroll
    for (int e = 0; e < E_; ++e) {
      const float rv = r[b * E_ + e];
      ax += rv * wv[e].x;
      ay += rv * wv[e].y;
    }
    const uint_t v = (uint_t)f2bf_rne(ax) | ((uint_t)f2bf_rne(ay) << 16);
    *(uint_t*)&agg[(size_t)b * (CO_ * CI_) + base] = v;
  }
}

// ---------------------------------------------------------------------------
// Kernel 2: round-2 proven skeleton + (a) double-buffered tiles, ONE barrier
// per K-iter (prefetch k+1 overlaps compute k), (b) conflict-optimal B layout:
// 64B rows, 8B chunks XOR-swizzled by ((row>>1)&7) -> wave64 writes & b64
// frag reads both hit all 32 banks (4-cycle optimal).
// A path: global_load_lds w=16 into XOR-swizzled 16B slots (proven round 2).
// Grid (8, 168): blockIdx.x == XCD, y packs (b>>3, mt, nt) -> L2 locality.
// ---------------------------------------------------------------------------
#define BM 128
#define BN 128
#define BK 32
#define KIT (CI_ / BK)     // 12

__global__ __launch_bounds__(256) void moe_gemm(const float* __restrict__ X,
                                                const ushort_t* __restrict__ Agg,
                                                float* __restrict__ Out) {
  __shared__ __align__(16) ushort_t As[2][BM * BK];  // 2 x 512 swizzled 16B slots
  __shared__ __align__(16) ushort_t Bs[2][BN * BK];  // 2 x 128 rows x 64B

  const int tid  = threadIdx.x;
  const int lane = tid & 63;
  const int wave = tid >> 6;
  const int wm = wave & 1, wn = wave >> 1;

  // XCD-aware decomposition (proven round 2)
  const int bx = blockIdx.x;           // 0..7  == XCD id
  const int by = blockIdx.y;           // 0..167
  const int bg  = by / 21;
  const int rem = by - bg * 21;
  const int mt  = rem / 7;
  const int nt  = rem - mt * 7;
  const int b   = bg * 8 + bx;

  const ushort_t* Ab = Agg + (size_t)b * CO_ * CI_ + mt * BM * CI_;
  const float*    Xb = X   + (size_t)b * CI_ * HW_;

  // B-staging coords: thread t handles row sn = t&127, k sub-offset (t>>7)*4
  const int sn  = tid & 127;
  const int sk4 = (tid >> 7) * 4;      // 0 or 4
  const int gn  = nt * BN + sn;
  const int gnc = gn < HW_ ? gn : (HW_ - 1);   // clamp (garbage cols discarded)
  const float* Xcol = Xb + gnc;
  const int swz = (sn >> 1) & 7;       // B chunk swizzle for this row

  // A-staging source (m,q) for slots s = tid, tid+256 (proven round 2)
  const int sm0 = tid >> 2,           sq0 = (tid & 3) ^ ((tid >> 3) & 3);
  const int sm1 = (tid + 256) >> 2,   sq1 = (tid & 3) ^ (((tid + 256) >> 3) & 3);

  const int l15 = lane & 15;
  const int lq  = lane >> 4;
  const int xqA = lq ^ ((l15 >> 1) & 3);   // swizzled q for A-frag reads

  f32x4 acc[4][4];
#pragma unroll
  for (int i = 0; i < 4; ++i)
#pragma unroll
    for (int j = 0; j < 4; ++j)
      acc[i][j] = (f32x4)0.f;

  float bv[16];                        // B prefetch registers (tile k+1)

  // ---- helpers (inlined) ----
  auto stage_a = [&](int k0, int bsel) {
    const ushort_t* src0 = Ab + sm0 * CI_ + k0 + sq0 * 8;
    __builtin_amdgcn_global_load_lds(
        (const __attribute__((address_space(1))) uint_t*)src0,
        (__attribute__((address_space(3))) uint_t*)&As[bsel][tid * 8], 16, 0, 0);
    const ushort_t* src1 = Ab + sm1 * CI_ + k0 + sq1 * 8;
    __builtin_amdgcn_global_load_lds(
        (const __attribute__((address_space(1))) uint_t*)src1,
        (__attribute__((address_space(3))) uint_t*)&As[bsel][(tid + 256) * 8], 16, 0, 0);
  };
  auto load_b = [&](int k0) {
#pragma unroll
    for (int j = 0; j < 4; ++j) {
      const float* p = Xcol + (size_t)(k0 + j * 8 + sk4) * HW_;
#pragma unroll
      for (int c = 0; c < 4; ++c)
        bv[j * 4 + c] = p[c * HW_];
    }
  };
  auto pack_b = [&](int bsel) {
#pragma unroll
    for (int j = 0; j < 4; ++j) {
      const int c  = 2 * j + (sk4 >> 2);       // logical 8B chunk in row
      const int pc = c ^ swz;                  // physical chunk
      const uint_t lo = pack_bf16_trunc(bv[j * 4 + 0], bv[j * 4 + 1]);
      const uint_t hi = pack_bf16_trunc(bv[j * 4 + 2], bv[j * 4 + 3]);
      *(uint2*)&Bs[bsel][sn * 32 + pc * 4] = make_uint2(lo, hi);
    }
  };

  // ---- prologue: stage k-tile 0 into buffer 0 ----
  stage_a(0, 0);
  load_b(0);
  pack_b(0);

  int buf = 0;
  for (int kk = 0; kk < KIT; ++kk) {
    __syncthreads();                   // drains A-DMA(kk) + B-writes(kk)
    const int nb = buf ^ 1;
    if (kk + 1 < KIT) {
      stage_a((kk + 1) * BK, nb);      // async, lands during our MFMA block
      load_b((kk + 1) * BK);           // global->VGPR, consumed after MFMA
    }
    // ---- frags + 16 MFMA from buffer `buf` ----
    bf16x8 a[4], bb[4];
#pragma unroll
    for (int mf = 0; mf < 4; ++mf) {
      const int m = wm * 64 + mf * 16 + l15;
      a[mf] = *(const bf16x8*)&As[buf][(m * 4 + xqA) * 8];
    }
#pragma unroll
    for (int nf = 0; nf < 4; ++nf) {
      const int rn = wn * 64 + nf * 16 + l15;
      const int h  = (rn >> 1) & 7;
      const int p0 = (2 * lq) ^ h;               // physical chunk of k [8lq,8lq+4)
      const uint2 lo = *(const uint2*)&Bs[buf][rn * 32 + p0 * 4];
      const uint2 hi = *(const uint2*)&Bs[buf][rn * 32 + (p0 ^ 1) * 4];
      uint32x4 u;
      u[0] = lo.x; u[1] = lo.y; u[2] = hi.x; u[3] = hi.y;
      bb[nf] = __builtin_bit_cast(bf16x8, u);
    }
#pragma unroll
    for (int mf = 0; mf < 4; ++mf)
#pragma unroll
      for (int nf = 0; nf < 4; ++nf)
        acc[mf][nf] = __builtin_amdgcn_mfma_f32_16x16x32_bf16(a[mf], bb[nf],
                                                              acc[mf][nf], 0, 0, 0);
    if (kk + 1 < KIT)
      pack_b(nb);                      // write tile k+1's B into the other buffer
    buf = nb;
  }

  // ---- Epilogue (proven round 2): C/D col=lane&15, row=(lane>>4)*4+reg ----
  float* Ob = Out + (size_t)b * CO_ * HW_;
#pragma unroll
  for (int mf = 0; mf < 4; ++mf) {
#pragma unroll
    for (int nf = 0; nf < 4; ++nf) {
      const int n = nt * BN + wn * 64 + nf * 16 + l15;
      if (n < HW_) {
        const int mbase = mt * BM + wm * 64 + mf * 16 + lq * 4;
#pragma unroll
        for (int r = 0; r < 4; ++r)
          Ob[(size_t)(mbase + r) * HW_ + n] = acc[mf][nf][r];
      }
    }
  }
}

// ---------------------------------------------------------------------------
extern "C" void kernel_launch(void* const* d_in, const int* in_sizes, int n_in,
                              void* d_out, int out_size, void* d_ws, size_t ws_size,
                              hipStream_t stream) {
  const float* x  = (const float*)d_in[0];  // [64,384,28,28] f32
  const float* rw = (const float*)d_in[1];  // [64,8] f32
  const float* w  = (const float*)d_in[2];  // [8,384,384] f32
  float* out = (float*)d_out;               // [64,384,28,28] f32
  ushort_t* agg = (ushort_t*)d_ws;          // [64,384,384] bf16 = 18.9 MB scratch

  agg_kernel<<<dim3((CO_ * CI_) / 512, 4), 256, 0, stream>>>(rw, w, agg);
  moe_gemm<<<dim3(8, 168), 256, 0, stream>>>(x, agg, out);
}